// Round 2
// baseline (308.730 us; speedup 1.0000x reference)
//
#include <hip/hip_runtime.h>
#include <hip/hip_bf16.h>

// GeometricLinear: out[b,i,r] = sum_{j,p} x[b,j,p] * Wc[i,j,p,r] + bias[i,r]
// Wc[i,j,p,r] = STAB[r][p] * weight[i,j,QTAB[r][p]]  (Cl(3,0) Cayley = signed perm)
// => single bf16 GEMM: out[4096][4096] = X[4096][4096] * Wc_bt[4096][4096]^T + bias
//    M = BATCH = 4096, N = OUT_F*8 = 4096, K = IN_F*8 = 4096

#define MDIM 4096
#define NDIM 4096
#define KDIM 4096

typedef __attribute__((ext_vector_type(8))) __bf16 bf16x8;
typedef __attribute__((ext_vector_type(4))) float f32x4;
typedef __attribute__((ext_vector_type(8))) unsigned short ushort8;

__device__ __forceinline__ unsigned short f2bf(float f) {
  unsigned int u = __builtin_bit_cast(unsigned int, f);
  u += 0x7fffu + ((u >> 16) & 1u);   // round-to-nearest-even
  return (unsigned short)(u >> 16);
}

// For output blade r, input blade p: q index and sign such that
// Wc[i,j,p,r] = STAB[r][p] * w[i,j,QTAB[r][p]]
__device__ const int QTAB[8][8] = {
  {0,1,2,3,4,5,6,7},
  {1,0,4,5,2,3,7,6},
  {2,4,0,6,1,7,3,5},
  {3,5,6,0,7,1,2,4},
  {4,2,1,7,0,6,5,3},
  {5,3,7,1,6,0,4,2},
  {6,7,3,2,5,4,0,1},
  {7,6,5,4,3,2,1,0},
};
__device__ const float STAB[8][8] = {
  { 1, 1, 1, 1,-1,-1,-1,-1},
  { 1, 1,-1,-1, 1, 1,-1,-1},
  { 1, 1, 1,-1,-1, 1, 1, 1},
  { 1, 1, 1, 1,-1,-1,-1,-1},
  { 1, 1,-1, 1, 1,-1, 1, 1},
  { 1, 1,-1,-1, 1, 1,-1,-1},
  { 1, 1, 1,-1,-1, 1, 1, 1},
  { 1, 1,-1, 1, 1,-1, 1, 1},
};

// ---- kernel 1: cast x (f32) -> Xb (bf16), pure elementwise, 8 elems/thread ----
__global__ __launch_bounds__(256) void cast_x_kernel(
    const float* __restrict__ X, unsigned short* __restrict__ Xb) {
  const size_t t = (size_t)blockIdx.x * 256 + threadIdx.x;  // 2^21 threads
  const float4* p = (const float4*)(X + t * 8);
  float4 a = p[0], b = p[1];
  ushort8 o;
  o[0] = f2bf(a.x); o[1] = f2bf(a.y); o[2] = f2bf(a.z); o[3] = f2bf(a.w);
  o[4] = f2bf(b.x); o[5] = f2bf(b.y); o[6] = f2bf(b.z); o[7] = f2bf(b.w);
  *(ushort8*)(Xb + t * 8) = o;
}

// ---- kernel 2: build Wb[n][k] = STAB[r][p]*w[i][j][QTAB[r][p]] as bf16 ----
// n = i*8+r (rows of B^T), k = j*8+p. One thread per (n, j): reads 8 w, writes 8 bf16.
__global__ __launch_bounds__(256) void build_wc_kernel(
    const float* __restrict__ W, unsigned short* __restrict__ Wb) {
  const size_t t = (size_t)blockIdx.x * 256 + threadIdx.x;  // 4096*512 threads
  const int n = (int)(t >> 9);
  const int j = (int)(t & 511);
  const int i = n >> 3;
  const int r = n & 7;
  const float* wp = W + ((size_t)i * 512 + j) * 8;
  float4 w0 = *(const float4*)wp;
  float4 w1 = *(const float4*)(wp + 4);
  float w[8] = {w0.x, w0.y, w0.z, w0.w, w1.x, w1.y, w1.z, w1.w};
  ushort8 o;
#pragma unroll
  for (int p = 0; p < 8; ++p) {
    o[p] = f2bf(STAB[r][p] * w[QTAB[r][p]]);
  }
  *(ushort8*)(Wb + (size_t)n * KDIM + j * 8) = o;
}

// ---- kernel 3: bf16 GEMM C = A * B^T + bias, m97-structure ----
// 128x128 tile, BK=64, 4 waves (2x2), 16x16x32 MFMA, global_load_lds width 16.
typedef const __attribute__((address_space(1))) unsigned int as1_uint;
typedef __attribute__((address_space(3))) unsigned int as3_uint;

__device__ __forceinline__ void gload_lds16(const unsigned short* g,
                                            unsigned short* l) {
  __builtin_amdgcn_global_load_lds((as1_uint*)g, (as3_uint*)l, 16, 0, 0);
}

__global__ __launch_bounds__(256, 2) void gemm_bt_bias(
    const unsigned short* __restrict__ A,   // [M][K] bf16 bits
    const unsigned short* __restrict__ B,   // [N][K] bf16 bits
    const float* __restrict__ bias,         // [N]
    float* __restrict__ C) {                // [M][N] f32
  __shared__ unsigned short As[128 * 64];
  __shared__ unsigned short Bs[128 * 64];

  const int tid = threadIdx.x;
  const int wid = tid >> 6;      // 0..3
  const int lane = tid & 63;
  const int wm = wid >> 1;       // wave row 0..1
  const int wn = wid & 1;        // wave col 0..1
  const int brow = blockIdx.y * 128;
  const int bcol = blockIdx.x * 128;

  f32x4 acc[4][4];
#pragma unroll
  for (int m = 0; m < 4; ++m)
#pragma unroll
    for (int n = 0; n < 4; ++n) acc[m][n] = (f32x4){0.f, 0.f, 0.f, 0.f};

  const int l_row = lane >> 3;         // 0..7 within 8-row chunk
  const int l_col = (lane & 7) * 8;    // elem col 0..56 (16B granules)
  const int fr = lane & 15;            // fragment row/col
  const int fq = lane >> 4;            // 0..3 k-group / row-group

  for (int kt = 0; kt < KDIM; kt += 64) {
    // stage A[128][64] and B[128][64]: 16 x 1KB chunks each tile, 4 per wave
#pragma unroll
    for (int t = 0; t < 4; ++t) {
      const int c = t * 4 + wid;           // chunk 0..15 (wave-uniform)
      const int row = c * 8 + l_row;
      gload_lds16(A + (size_t)(brow + row) * KDIM + kt + l_col, As + c * 512);
      gload_lds16(B + (size_t)(bcol + row) * KDIM + kt + l_col, Bs + c * 512);
    }
    __syncthreads();

#pragma unroll
    for (int ks = 0; ks < 2; ++ks) {
      const int kb = ks * 32 + fq * 8;   // k offset within row
      bf16x8 af[4], bv[4];
#pragma unroll
      for (int m = 0; m < 4; ++m)
        af[m] = *(const bf16x8*)(As + (wm * 64 + m * 16 + fr) * 64 + kb);
#pragma unroll
      for (int n = 0; n < 4; ++n)
        bv[n] = *(const bf16x8*)(Bs + (wn * 64 + n * 16 + fr) * 64 + kb);
#pragma unroll
      for (int m = 0; m < 4; ++m)
#pragma unroll
        for (int n = 0; n < 4; ++n)
          acc[m][n] = __builtin_amdgcn_mfma_f32_16x16x32_bf16(af[m], bv[n],
                                                              acc[m][n], 0, 0, 0);
    }
    __syncthreads();
  }

  // epilogue: C/D layout col = lane&15, row = (lane>>4)*4 + reg (m89-verified)
#pragma unroll
  for (int n = 0; n < 4; ++n) {
    const int col = bcol + wn * 64 + n * 16 + fr;
    const float bvs = bias[col];
#pragma unroll
    for (int m = 0; m < 4; ++m) {
      const int row0 = brow + wm * 64 + m * 16 + fq * 4;
#pragma unroll
      for (int j = 0; j < 4; ++j)
        C[(size_t)(row0 + j) * NDIM + col] = acc[m][n][j] + bvs;
    }
  }
}

extern "C" void kernel_launch(void* const* d_in, const int* in_sizes, int n_in,
                              void* d_out, int out_size, void* d_ws, size_t ws_size,
                              hipStream_t stream) {
  const float* x = (const float*)d_in[0];     // [4096,512,8]
  const float* w = (const float*)d_in[1];     // [512,512,8]
  const float* bias = (const float*)d_in[2];  // [512,8]
  float* out = (float*)d_out;                 // [4096,512,8]

  unsigned short* Xb = (unsigned short*)d_ws;           // 32 MiB
  unsigned short* Wb = Xb + (size_t)MDIM * KDIM;        // 32 MiB

  cast_x_kernel<<<8192, 256, 0, stream>>>(x, Xb);
  build_wc_kernel<<<8192, 256, 0, stream>>>(w, Wb);
  gemm_bt_bias<<<dim3(32, 32), 256, 0, stream>>>(Xb, Wb, bias, out);
}

// Round 3
// 258.961 us; speedup vs baseline: 1.1922x; 1.1922x over previous
//
#include <hip/hip_runtime.h>
#include <hip/hip_bf16.h>

// GeometricLinear: out[b,i,r] = sum_{j,p} x[b,j,p] * Wc[i,j,p,r] + bias[i,r]
// Wc[i,j,p,r] = STAB[r][p] * weight[i,j,QTAB[r][p]]  (Cl(3,0) Cayley = signed perm)
// => single bf16 GEMM: out[4096][4096] = X[4096][4096] * Wc_bt[4096][4096]^T + bias
// GEMM: 256x256 tile, BK=64, 8 waves (2x4), 8-phase K-split schedule (T1+T3+T4+T5).

#define MDIM 4096
#define NDIM 4096
#define KDIM 4096
#define KTILES 64   // KDIM/64

typedef __attribute__((ext_vector_type(8))) __bf16 bf16x8;
typedef __attribute__((ext_vector_type(4))) float f32x4;
typedef __attribute__((ext_vector_type(8))) unsigned short ushort8;

__device__ __forceinline__ unsigned short f2bf(float f) {
  unsigned int u = __builtin_bit_cast(unsigned int, f);
  u += 0x7fffu + ((u >> 16) & 1u);   // round-to-nearest-even
  return (unsigned short)(u >> 16);
}

__device__ const int QTAB[8][8] = {
  {0,1,2,3,4,5,6,7},
  {1,0,4,5,2,3,7,6},
  {2,4,0,6,1,7,3,5},
  {3,5,6,0,7,1,2,4},
  {4,2,1,7,0,6,5,3},
  {5,3,7,1,6,0,4,2},
  {6,7,3,2,5,4,0,1},
  {7,6,5,4,3,2,1,0},
};
__device__ const float STAB[8][8] = {
  { 1, 1, 1, 1,-1,-1,-1,-1},
  { 1, 1,-1,-1, 1, 1,-1,-1},
  { 1, 1, 1,-1,-1, 1, 1, 1},
  { 1, 1, 1, 1,-1,-1,-1,-1},
  { 1, 1,-1, 1, 1,-1, 1, 1},
  { 1, 1,-1,-1, 1, 1,-1,-1},
  { 1, 1, 1,-1,-1, 1, 1, 1},
  { 1, 1,-1, 1, 1,-1, 1, 1},
};

// ---- kernel 1: cast x (f32) -> Xb (bf16) ----
__global__ __launch_bounds__(256) void cast_x_kernel(
    const float* __restrict__ X, unsigned short* __restrict__ Xb) {
  const size_t t = (size_t)blockIdx.x * 256 + threadIdx.x;
  const float4* p = (const float4*)(X + t * 8);
  float4 a = p[0], b = p[1];
  ushort8 o;
  o[0] = f2bf(a.x); o[1] = f2bf(a.y); o[2] = f2bf(a.z); o[3] = f2bf(a.w);
  o[4] = f2bf(b.x); o[5] = f2bf(b.y); o[6] = f2bf(b.z); o[7] = f2bf(b.w);
  *(ushort8*)(Xb + t * 8) = o;
}

// ---- kernel 2: build Wb[n][k] = STAB[r][p]*w[i][j][QTAB[r][p]] as bf16 ----
__global__ __launch_bounds__(256) void build_wc_kernel(
    const float* __restrict__ W, unsigned short* __restrict__ Wb) {
  const size_t t = (size_t)blockIdx.x * 256 + threadIdx.x;
  const int n = (int)(t >> 9);
  const int j = (int)(t & 511);
  const int i = n >> 3;
  const int r = n & 7;
  const float* wp = W + ((size_t)i * 512 + j) * 8;
  float4 w0 = *(const float4*)wp;
  float4 w1 = *(const float4*)(wp + 4);
  float w[8] = {w0.x, w0.y, w0.z, w0.w, w1.x, w1.y, w1.z, w1.w};
  ushort8 o;
#pragma unroll
  for (int p = 0; p < 8; ++p) o[p] = f2bf(STAB[r][p] * w[QTAB[r][p]]);
  *(ushort8*)(Wb + (size_t)n * KDIM + j * 8) = o;
}

// ---- kernel 3: 256x256 8-phase bf16 GEMM, C = A*B^T + bias ----
typedef const __attribute__((address_space(1))) unsigned int as1_uint;
typedef __attribute__((address_space(3))) unsigned int as3_uint;

__device__ __forceinline__ void gload_lds16(const unsigned short* g,
                                            unsigned short* l) {
  __builtin_amdgcn_global_load_lds((as1_uint*)g, (as3_uint*)l, 16, 0, 0);
}

// Stage one half-tile [256 rows][32 K] (16 KiB) -> LDS slot (linear [256][32]).
// Each wave: 2 x gload_lds (2 KiB each); wave w covers rows [w*32, w*32+32).
__device__ __forceinline__ void stage_half(
    const unsigned short* __restrict__ G, int gbase_row, int tile, int kh,
    unsigned short* lds_slot, int wid, int lane) {
#pragma unroll
  for (int q = 0; q < 2; ++q) {
    const int c = wid * 2 + q;                       // chunk 0..15, 16 rows each
    const unsigned short* src = G
        + (size_t)(gbase_row + c * 16 + (lane >> 2)) * KDIM
        + tile * 64 + kh * 32 + (lane & 3) * 8;
    gload_lds16(src, lds_slot + c * 512);            // wave-uniform base
  }
}

#define BAR()  asm volatile("s_barrier" ::: "memory")
#define VM6()  asm volatile("s_waitcnt vmcnt(6)" ::: "memory")
#define VM0()  asm volatile("s_waitcnt vmcnt(0)" ::: "memory")
#define NOSTAGE (void)0

// One phase: 4(or 8) ds_read_b128 -> issue 1 half-tile stage -> [vmcnt] ->
// barrier -> 16 MFMA (setprio-bracketed) -> barrier.
#define PH(bufb, kk, mh, RDB, STAGE_STMT, VMC_STMT) do {                      \
    const unsigned short* As_ = &lds[(bufb)*4 + (kk)][0];                     \
    const unsigned short* Bs_ = &lds[(bufb)*4 + 2 + (kk)][0];                 \
    bf16x8 af[4];                                                             \
    _Pragma("unroll") for (int mi = 0; mi < 4; ++mi)                          \
      af[mi] = *(const bf16x8*)(As_ + (wm*128 + ((mh)*4+mi)*16 + fr)*32 + fq*8); \
    if (RDB) {                                                                \
      _Pragma("unroll") for (int n = 0; n < 4; ++n)                           \
        bfr[n] = *(const bf16x8*)(Bs_ + (wn*64 + n*16 + fr)*32 + fq*8);       \
    }                                                                         \
    STAGE_STMT;                                                               \
    VMC_STMT;                                                                 \
    BAR();                                                                    \
    __builtin_amdgcn_s_setprio(1);                                            \
    _Pragma("unroll") for (int mi = 0; mi < 4; ++mi)                          \
      _Pragma("unroll") for (int n = 0; n < 4; ++n)                           \
        acc[(mh)*4+mi][n] = __builtin_amdgcn_mfma_f32_16x16x32_bf16(          \
            af[mi], bfr[n], acc[(mh)*4+mi][n], 0, 0, 0);                      \
    __builtin_amdgcn_s_setprio(0);                                            \
    BAR();                                                                    \
  } while (0)

__global__ __launch_bounds__(512, 2) void gemm_bt_bias(
    const unsigned short* __restrict__ A,   // [M][K] bf16 bits
    const unsigned short* __restrict__ B,   // [N][K] bf16 bits
    const float* __restrict__ bias,         // [N]
    float* __restrict__ C) {                // [M][N] f32
  // 8 half-tile slots of 16 KiB: slot = buf*4 + mat*2 + khalf  (mat: A=0,B=1)
  __shared__ unsigned short lds[8][8192];   // 128 KiB

  const int tid = threadIdx.x;
  const int wid = tid >> 6;        // 0..7
  const int lane = tid & 63;
  const int wm = wid >> 2;         // 0..1 : wave row-half (128 rows)
  const int wn = wid & 3;          // 0..3 : wave col-quarter (64 cols)
  const int fr = lane & 15;
  const int fq = lane >> 4;

  // XCD-aware bijective swizzle (256 blocks, 256 % 8 == 0)
  const int raw = blockIdx.x;
  const int wg = (raw & 7) * 32 + (raw >> 3);
  const int brow = (wg >> 4) * 256;
  const int bcol = (wg & 15) * 256;

  f32x4 acc[8][4];
#pragma unroll
  for (int m = 0; m < 8; ++m)
#pragma unroll
    for (int n = 0; n < 4; ++n) acc[m][n] = (f32x4){0.f, 0.f, 0.f, 0.f};
  bf16x8 bfr[4];

  // Prologue: tile0 all 4 halves, tile1 {Bk0, Ak0, Bk1}; tile1.Ak1 comes in ph1.
  stage_half(A, brow, 0, 0, &lds[0][0], wid, lane);
  stage_half(A, brow, 0, 1, &lds[1][0], wid, lane);
  stage_half(B, bcol, 0, 0, &lds[2][0], wid, lane);
  stage_half(B, bcol, 0, 1, &lds[3][0], wid, lane);
  stage_half(A, brow, 1, 0, &lds[4][0], wid, lane);
  stage_half(B, bcol, 1, 0, &lds[6][0], wid, lane);
  stage_half(B, bcol, 1, 1, &lds[7][0], wid, lane);
  VM6();   // first 8 loads (all of tile0) landed
  BAR();

  // Main loop: iteration i computes tiles 2i (buf0) and 2i+1 (buf1).
  // Stage stream per iteration: ph1: buf1.Ak1<-t1 ; ph2..5: tile t0+2 ;
  // ph6..8: tile t1+2 {Bk0,Ak0,Bk1}. vmcnt(6) at ph4 & ph8 (2 loads/phase).
  for (int i = 0; i < KTILES / 2 - 1; ++i) {
    const int t0 = 2 * i, t1 = 2 * i + 1;
    PH(0, 0, 0, 1, stage_half(A, brow, t1,     1, &lds[5][0], wid, lane), NOSTAGE);
    PH(0, 0, 1, 0, stage_half(B, bcol, t0 + 2, 0, &lds[2][0], wid, lane), NOSTAGE);
    PH(0, 1, 0, 1, stage_half(A, brow, t0 + 2, 0, &lds[0][0], wid, lane), NOSTAGE);
    PH(0, 1, 1, 0, stage_half(B, bcol, t0 + 2, 1, &lds[3][0], wid, lane), VM6());
    PH(1, 0, 0, 1, stage_half(A, brow, t0 + 2, 1, &lds[1][0], wid, lane), NOSTAGE);
    PH(1, 0, 1, 0, stage_half(B, bcol, t1 + 2, 0, &lds[6][0], wid, lane), NOSTAGE);
    PH(1, 1, 0, 1, stage_half(A, brow, t1 + 2, 0, &lds[4][0], wid, lane), NOSTAGE);
    PH(1, 1, 1, 0, stage_half(B, bcol, t1 + 2, 1, &lds[7][0], wid, lane), VM6());
  }

  // Epilogue: tiles 62 (buf0), 63 (buf1); only ph1's stage (tile63.Ak1) remains.
  PH(0, 0, 0, 1, stage_half(A, brow, KTILES - 1, 1, &lds[5][0], wid, lane), NOSTAGE);
  PH(0, 0, 1, 0, NOSTAGE, NOSTAGE);
  PH(0, 1, 0, 1, NOSTAGE, NOSTAGE);
  PH(0, 1, 1, 0, NOSTAGE, VM0());
  PH(1, 0, 0, 1, NOSTAGE, NOSTAGE);
  PH(1, 0, 1, 0, NOSTAGE, NOSTAGE);
  PH(1, 1, 0, 1, NOSTAGE, NOSTAGE);
  PH(1, 1, 1, 0, NOSTAGE, NOSTAGE);

  // C-write: D layout col = lane&15, row = (lane>>4)*4 + j (m89-verified)
#pragma unroll
  for (int n = 0; n < 4; ++n) {
    const int col = bcol + wn * 64 + n * 16 + fr;
    const float bvs = bias[col];
#pragma unroll
    for (int m = 0; m < 8; ++m) {
      const int row0 = brow + wm * 128 + m * 16 + fq * 4;
#pragma unroll
      for (int j = 0; j < 4; ++j)
        C[(size_t)(row0 + j) * NDIM + col] = acc[m][n][j] + bvs;
    }
  }
}

extern "C" void kernel_launch(void* const* d_in, const int* in_sizes, int n_in,
                              void* d_out, int out_size, void* d_ws, size_t ws_size,
                              hipStream_t stream) {
  const float* x = (const float*)d_in[0];     // [4096,512,8]
  const float* w = (const float*)d_in[1];     // [512,512,8]
  const float* bias = (const float*)d_in[2];  // [512,8]
  float* out = (float*)d_out;                 // [4096,512,8]

  unsigned short* Xb = (unsigned short*)d_ws;           // 32 MiB
  unsigned short* Wb = Xb + (size_t)MDIM * KDIM;        // 32 MiB

  cast_x_kernel<<<8192, 256, 0, stream>>>(x, Xb);
  build_wc_kernel<<<8192, 256, 0, stream>>>(w, Wb);
  gemm_bt_bias<<<256, 512, 0, stream>>>(Xb, Wb, bias, out);
}

// Round 4
// 245.563 us; speedup vs baseline: 1.2572x; 1.0546x over previous
//
#include <hip/hip_runtime.h>
#include <hip/hip_bf16.h>

// GeometricLinear: out[b,i,r] = sum_{j,p} x[b,j,p] * Wc[i,j,p,r] + bias[i,r]
// Wc[i,j,p,r] = STAB[r][p] * weight[i,j,QTAB[r][p]]  (Cl(3,0) Cayley = signed perm)
// => single bf16 GEMM: out[4096][4096] = X[4096][4096] * Wc_bt[4096][4096]^T + bias
// GEMM: 256x256 tile, BK=64, 8 waves (2x4), 8-phase K-split schedule
// (T1 swizzle + T3/T4 counted vmcnt + T5 setprio + T2-style XOR LDS swizzle).

#define MDIM 4096
#define NDIM 4096
#define KDIM 4096
#define KTILES 64   // KDIM/64

typedef __attribute__((ext_vector_type(8))) __bf16 bf16x8;
typedef __attribute__((ext_vector_type(4))) float f32x4;
typedef __attribute__((ext_vector_type(8))) unsigned short ushort8;

__device__ __forceinline__ unsigned short f2bf(float f) {
  unsigned int u = __builtin_bit_cast(unsigned int, f);
  u += 0x7fffu + ((u >> 16) & 1u);   // round-to-nearest-even
  return (unsigned short)(u >> 16);
}

// Compile-time Cayley tables (constexpr => folded to immediates under unroll).
static constexpr int QTAB[8][8] = {
  {0,1,2,3,4,5,6,7},
  {1,0,4,5,2,3,7,6},
  {2,4,0,6,1,7,3,5},
  {3,5,6,0,7,1,2,4},
  {4,2,1,7,0,6,5,3},
  {5,3,7,1,6,0,4,2},
  {6,7,3,2,5,4,0,1},
  {7,6,5,4,3,2,1,0},
};
// sign bit to XOR into the bf16 (0x8000 where STAB == -1)
static constexpr unsigned short SBIT[8][8] = {
  {0,0,0,0,0x8000,0x8000,0x8000,0x8000},
  {0,0,0x8000,0x8000,0,0,0x8000,0x8000},
  {0,0,0,0x8000,0x8000,0,0,0},
  {0,0,0,0,0x8000,0x8000,0x8000,0x8000},
  {0,0,0x8000,0,0,0x8000,0,0},
  {0,0,0x8000,0x8000,0,0,0x8000,0x8000},
  {0,0,0,0x8000,0x8000,0,0,0},
  {0,0,0x8000,0,0,0x8000,0,0},
};

// ---- kernel 1: cast x (f32) -> Xb (bf16) ----
__global__ __launch_bounds__(256) void cast_x_kernel(
    const float* __restrict__ X, unsigned short* __restrict__ Xb) {
  const size_t t = (size_t)blockIdx.x * 256 + threadIdx.x;
  const float4* p = (const float4*)(X + t * 8);
  float4 a = p[0], b = p[1];
  ushort8 o;
  o[0] = f2bf(a.x); o[1] = f2bf(a.y); o[2] = f2bf(a.z); o[3] = f2bf(a.w);
  o[4] = f2bf(b.x); o[5] = f2bf(b.y); o[6] = f2bf(b.z); o[7] = f2bf(b.w);
  *(ushort8*)(Xb + t * 8) = o;
}

// ---- kernel 2: build Wb[n][k], one thread per (i,j), ALL indices static ----
// n = i*8+r, k = j*8+p ; Wb[n][k] = SBIT[r][p] ^ bf16(w[i,j,QTAB[r][p]])
__global__ __launch_bounds__(256) void build_wc_kernel(
    const float* __restrict__ W, unsigned short* __restrict__ Wb) {
  const int t = blockIdx.x * 256 + threadIdx.x;   // t = i*512 + j, 512*512 total
  const int i = t >> 9;
  const int j = t & 511;
  const float4 w0 = *(const float4*)(W + (size_t)t * 8);
  const float4 w1 = *(const float4*)(W + (size_t)t * 8 + 4);
  const unsigned short b[8] = {f2bf(w0.x), f2bf(w0.y), f2bf(w0.z), f2bf(w0.w),
                               f2bf(w1.x), f2bf(w1.y), f2bf(w1.z), f2bf(w1.w)};
#pragma unroll
  for (int r = 0; r < 8; ++r) {
    ushort8 o;
#pragma unroll
    for (int p = 0; p < 8; ++p)
      o[p] = (unsigned short)(b[QTAB[r][p]] ^ SBIT[r][p]);
    *(ushort8*)(Wb + (size_t)(i * 8 + r) * KDIM + j * 8) = o;
  }
}

// ---- kernel 3: 256x256 8-phase bf16 GEMM, C = A*B^T + bias ----
typedef const __attribute__((address_space(1))) unsigned int as1_uint;
typedef __attribute__((address_space(3))) unsigned int as3_uint;

__device__ __forceinline__ void gload_lds16(const unsigned short* g,
                                            unsigned short* l) {
  __builtin_amdgcn_global_load_lds((as1_uint*)g, (as3_uint*)l, 16, 0, 0);
}

// Stage one half-tile [256 rows][32 K] (16 KiB) -> LDS slot (linear dest).
// XOR swizzle (rule #21): LDS granule (row, s) holds k-seg q = s ^ ((row>>1)&3),
// applied by permuting the per-lane GLOBAL source column; reads use the same XOR.
__device__ __forceinline__ void stage_half(
    const unsigned short* __restrict__ G, int gbase_row, int tile, int kh,
    unsigned short* lds_slot, int wid, int lane) {
  const int colswz = ((lane & 3) ^ ((lane >> 3) & 3)) * 8;
#pragma unroll
  for (int q = 0; q < 2; ++q) {
    const int c = wid * 2 + q;                       // chunk 0..15, 16 rows each
    const unsigned short* src = G
        + (size_t)(gbase_row + c * 16 + (lane >> 2)) * KDIM
        + tile * 64 + kh * 32 + colswz;
    gload_lds16(src, lds_slot + c * 512);            // wave-uniform base
  }
}

#define BAR()  asm volatile("s_barrier" ::: "memory")
#define VM6()  asm volatile("s_waitcnt vmcnt(6)" ::: "memory")
#define VM0()  asm volatile("s_waitcnt vmcnt(0)" ::: "memory")
#define NOSTAGE (void)0

// One phase: 4(or 8) ds_read_b128 -> issue 1 half-tile stage -> [vmcnt] ->
// barrier -> 16 MFMA (setprio-bracketed) -> barrier.
#define PH(bufb, kk, mh, RDB, STAGE_STMT, VMC_STMT) do {                      \
    const unsigned short* As_ = &lds[(bufb)*4 + (kk)][0];                     \
    const unsigned short* Bs_ = &lds[(bufb)*4 + 2 + (kk)][0];                 \
    bf16x8 af[4];                                                             \
    _Pragma("unroll") for (int mi = 0; mi < 4; ++mi)                          \
      af[mi] = *(const bf16x8*)(As_ + (wm*128 + ((mh)*4+mi)*16 + fr)*32 + fqs*8); \
    if (RDB) {                                                                \
      _Pragma("unroll") for (int n = 0; n < 4; ++n)                           \
        bfr[n] = *(const bf16x8*)(Bs_ + (wn*64 + n*16 + fr)*32 + fqs*8);      \
    }                                                                         \
    STAGE_STMT;                                                               \
    VMC_STMT;                                                                 \
    BAR();                                                                    \
    __builtin_amdgcn_s_setprio(1);                                            \
    _Pragma("unroll") for (int mi = 0; mi < 4; ++mi)                          \
      _Pragma("unroll") for (int n = 0; n < 4; ++n)                           \
        acc[(mh)*4+mi][n] = __builtin_amdgcn_mfma_f32_16x16x32_bf16(          \
            af[mi], bfr[n], acc[(mh)*4+mi][n], 0, 0, 0);                      \
    __builtin_amdgcn_s_setprio(0);                                            \
    BAR();                                                                    \
  } while (0)

__global__ __launch_bounds__(512, 2) void gemm_bt_bias(
    const unsigned short* __restrict__ A,   // [M][K] bf16 bits
    const unsigned short* __restrict__ B,   // [N][K] bf16 bits
    const float* __restrict__ bias,         // [N]
    float* __restrict__ C) {                // [M][N] f32
  // 8 half-tile slots of 16 KiB: slot = buf*4 + mat*2 + khalf  (mat: A=0,B=1)
  __shared__ unsigned short lds[8][8192];   // 128 KiB

  const int tid = threadIdx.x;
  const int wid = tid >> 6;        // 0..7
  const int lane = tid & 63;
  const int wm = wid >> 2;         // 0..1 : wave row-half (128 rows)
  const int wn = wid & 3;          // 0..3 : wave col-quarter (64 cols)
  const int fr = lane & 15;
  const int fq = lane >> 4;
  const int fqs = fq ^ ((fr >> 1) & 3);   // swizzled k-seg for LDS reads

  // XCD-aware bijective swizzle (256 blocks, 256 % 8 == 0)
  const int raw = blockIdx.x;
  const int wg = (raw & 7) * 32 + (raw >> 3);
  const int brow = (wg >> 4) * 256;
  const int bcol = (wg & 15) * 256;

  f32x4 acc[8][4];
#pragma unroll
  for (int m = 0; m < 8; ++m)
#pragma unroll
    for (int n = 0; n < 4; ++n) acc[m][n] = (f32x4){0.f, 0.f, 0.f, 0.f};
  bf16x8 bfr[4];

  // Prologue: tile0 all 4 halves, tile1 {Bk0, Ak0, Bk1}; tile1.Ak1 comes in ph1.
  stage_half(A, brow, 0, 0, &lds[0][0], wid, lane);
  stage_half(A, brow, 0, 1, &lds[1][0], wid, lane);
  stage_half(B, bcol, 0, 0, &lds[2][0], wid, lane);
  stage_half(B, bcol, 0, 1, &lds[3][0], wid, lane);
  stage_half(A, brow, 1, 0, &lds[4][0], wid, lane);
  stage_half(B, bcol, 1, 0, &lds[6][0], wid, lane);
  stage_half(B, bcol, 1, 1, &lds[7][0], wid, lane);
  VM6();   // first 8 loads (all of tile0) landed
  BAR();

  // Main loop: iteration i computes tiles 2i (buf0) and 2i+1 (buf1).
  // Stage stream per iteration: ph1: buf1.Ak1<-t1 ; ph2..5: tile t0+2 ;
  // ph6..8: tile t1+2 {Bk0,Ak0,Bk1}. vmcnt(6) at ph4 & ph8 (2 loads/phase).
  for (int i = 0; i < KTILES / 2 - 1; ++i) {
    const int t0 = 2 * i, t1 = 2 * i + 1;
    PH(0, 0, 0, 1, stage_half(A, brow, t1,     1, &lds[5][0], wid, lane), NOSTAGE);
    PH(0, 0, 1, 0, stage_half(B, bcol, t0 + 2, 0, &lds[2][0], wid, lane), NOSTAGE);
    PH(0, 1, 0, 1, stage_half(A, brow, t0 + 2, 0, &lds[0][0], wid, lane), NOSTAGE);
    PH(0, 1, 1, 0, stage_half(B, bcol, t0 + 2, 1, &lds[3][0], wid, lane), VM6());
    PH(1, 0, 0, 1, stage_half(A, brow, t0 + 2, 1, &lds[1][0], wid, lane), NOSTAGE);
    PH(1, 0, 1, 0, stage_half(B, bcol, t1 + 2, 0, &lds[6][0], wid, lane), NOSTAGE);
    PH(1, 1, 0, 1, stage_half(A, brow, t1 + 2, 0, &lds[4][0], wid, lane), NOSTAGE);
    PH(1, 1, 1, 0, stage_half(B, bcol, t1 + 2, 1, &lds[7][0], wid, lane), VM6());
  }

  // Epilogue: tiles 62 (buf0), 63 (buf1); only ph1's stage (tile63.Ak1) remains.
  PH(0, 0, 0, 1, stage_half(A, brow, KTILES - 1, 1, &lds[5][0], wid, lane), NOSTAGE);
  PH(0, 0, 1, 0, NOSTAGE, NOSTAGE);
  PH(0, 1, 0, 1, NOSTAGE, NOSTAGE);
  PH(0, 1, 1, 0, NOSTAGE, VM0());
  PH(1, 0, 0, 1, NOSTAGE, NOSTAGE);
  PH(1, 0, 1, 0, NOSTAGE, NOSTAGE);
  PH(1, 1, 0, 1, NOSTAGE, NOSTAGE);
  PH(1, 1, 1, 0, NOSTAGE, NOSTAGE);

  // C-write: D layout col = lane&15, row = (lane>>4)*4 + j (m89-verified)
#pragma unroll
  for (int n = 0; n < 4; ++n) {
    const int col = bcol + wn * 64 + n * 16 + fr;
    const float bvs = bias[col];
#pragma unroll
    for (int m = 0; m < 8; ++m) {
      const int row0 = brow + wm * 128 + m * 16 + fq * 4;
#pragma unroll
      for (int j = 0; j < 4; ++j)
        C[(size_t)(row0 + j) * NDIM + col] = acc[m][n][j] + bvs;
    }
  }
}

extern "C" void kernel_launch(void* const* d_in, const int* in_sizes, int n_in,
                              void* d_out, int out_size, void* d_ws, size_t ws_size,
                              hipStream_t stream) {
  const float* x = (const float*)d_in[0];     // [4096,512,8]
  const float* w = (const float*)d_in[1];     // [512,512,8]
  const float* bias = (const float*)d_in[2];  // [512,8]
  float* out = (float*)d_out;                 // [4096,512,8]

  unsigned short* Xb = (unsigned short*)d_ws;           // 32 MiB
  unsigned short* Wb = Xb + (size_t)MDIM * KDIM;        // 32 MiB

  cast_x_kernel<<<8192, 256, 0, stream>>>(x, Xb);
  build_wc_kernel<<<1024, 256, 0, stream>>>(w, Wb);
  gemm_bt_bias<<<256, 512, 0, stream>>>(Xb, Wb, bias, out);
}